// Round 1
// baseline (173.100 us; speedup 1.0000x reference)
//
#include <hip/hip_runtime.h>
#include <float.h>

#define B 16
#define H 256
#define W 256
#define C 64
#define TH 16
#define TW 16
#define NTH (H / TH)   // 16 h-tiles
#define NTW (W / TW)   // 16 w-tiles

// ---------------------------------------------------------------------------
// k_tilemax: one pass over input.
//   hTile[b][t][w][c] = max over h in tile t of in[b,h,w,c]
//   wTile[b][h][s][c] = max over w in tile s of in[b,h,w,c]
// grid = B*NTH*(W/64) = 1024 blocks, 256 threads.
// thread: c = tid&63, wg = tid>>6; owns w = wq*64 + wg*16 + j, j in [0,16)
// (exactly one w-tile per thread). All loads/stores: lane=c -> 256B coalesced.
// ---------------------------------------------------------------------------
__global__ __launch_bounds__(256) void k_tilemax(const float* __restrict__ in,
                                                 float* __restrict__ hTile,
                                                 float* __restrict__ wTile)
{
    int blk = blockIdx.x;
    int wq = blk & 3;                 // which 64-wide w chunk
    int t  = (blk >> 2) & (NTH - 1);  // h-tile
    int b  = blk >> 6;
    int tid = threadIdx.x;
    int c  = tid & 63;
    int wg = tid >> 6;                // 0..3
    int wbase = wq * 64 + wg * 16;
    int s = wbase / TW;               // w-tile index

    float hrun[16];
#pragma unroll
    for (int j = 0; j < 16; ++j) hrun[j] = -FLT_MAX;

    int h0 = t * TH;
    for (int hh = 0; hh < TH; ++hh) {
        int h = h0 + hh;
        const float* row = in + ((size_t)(b * H + h) * W + wbase) * C + c;
        float wmax = -FLT_MAX;
#pragma unroll
        for (int j = 0; j < 16; ++j) {
            float v = row[j * C];
            hrun[j] = fmaxf(hrun[j], v);
            wmax = fmaxf(wmax, v);
        }
        wTile[((size_t)(b * H + h) * NTW + s) * C + c] = wmax;
    }
    float* hout = hTile + ((size_t)(b * NTH + t) * W + wbase) * C + c;
#pragma unroll
    for (int j = 0; j < 16; ++j) hout[j * C] = hrun[j];
}

// ---------------------------------------------------------------------------
// k_sufscan: in-place EXCLUSIVE suffix max over a 16-long scan dim.
// layout: [outer][16][inner]; one thread per (outer, inner) column.
// inner is a power of two; pass log2(inner) as `shift`.
// ---------------------------------------------------------------------------
__global__ __launch_bounds__(256) void k_sufscan(float* __restrict__ buf,
                                                 int total, int shift)
{
    int idx = blockIdx.x * 256 + threadIdx.x;
    if (idx >= total) return;
    int inner = 1 << shift;
    int o = idx >> shift;
    int i = idx & (inner - 1);
    float* p = buf + ((size_t)o * 16) * inner + i;
    float v[16];
#pragma unroll
    for (int tt = 0; tt < 16; ++tt) v[tt] = p[tt * inner];
    float run = -FLT_MAX;
#pragma unroll
    for (int tt = 15; tt >= 0; --tt) {
        float nv = v[tt];
        v[tt] = run;              // exclusive: max over strictly-later tiles
        run = fmaxf(run, nv);
    }
#pragma unroll
    for (int tt = 0; tt < 16; ++tt) p[tt * inner] = v[tt];
}

// ---------------------------------------------------------------------------
// k_final: out = max(local h-suffix, hSuf) + max(local w-suffix, wSuf)
// Same decomposition as k_tilemax; block index reversed so the input re-read
// starts from the L3-resident tail of k_tilemax's pass.
// hrun[j] is seeded with the exclusive h-tile suffix, then updated with rows
// h descending -> after update it is the full inclusive h-suffix at (h, w+j).
// ws is seeded with the exclusive w-tile suffix, then accumulates j=15..0 ->
// full inclusive w-suffix at (h, w+j).
// ---------------------------------------------------------------------------
__global__ __launch_bounds__(256) void k_final(const float* __restrict__ in,
                                               const float* __restrict__ hSuf,
                                               const float* __restrict__ wSuf,
                                               float* __restrict__ out)
{
    int blk = (gridDim.x - 1) - blockIdx.x;   // reversed for L3 tail reuse
    int wq = blk & 3;
    int t  = (blk >> 2) & (NTH - 1);
    int b  = blk >> 6;
    int tid = threadIdx.x;
    int c  = tid & 63;
    int wg = tid >> 6;
    int wbase = wq * 64 + wg * 16;
    int s = wbase / TW;

    float hrun[16];
    const float* hs = hSuf + ((size_t)(b * NTH + t) * W + wbase) * C + c;
#pragma unroll
    for (int j = 0; j < 16; ++j) hrun[j] = hs[j * C];

    int h0 = t * TH;
    for (int hh = TH - 1; hh >= 0; --hh) {
        int h = h0 + hh;
        const float* row = in + ((size_t)(b * H + h) * W + wbase) * C + c;
        float v[16];
#pragma unroll
        for (int j = 0; j < 16; ++j) {
            v[j] = row[j * C];
            hrun[j] = fmaxf(hrun[j], v[j]);
        }
        float ws = wSuf[((size_t)(b * H + h) * NTW + s) * C + c];
        float* orow = out + ((size_t)(b * H + h) * W + wbase) * C + c;
#pragma unroll
        for (int j = 15; j >= 0; --j) {
            ws = fmaxf(ws, v[j]);
            orow[j * C] = hrun[j] + ws;
        }
    }
}

// ---------------------------------------------------------------------------
// Fallback (no workspace): two serial-scan kernels, fully coalesced.
// ---------------------------------------------------------------------------
__global__ __launch_bounds__(256) void k_wscan(const float* __restrict__ in,
                                               float* __restrict__ out)
{
    int idx = blockIdx.x * 256 + threadIdx.x;   // (b*H + h)*C + c
    int c  = idx & 63;
    int bh = idx >> 6;
    const float* p = in + (size_t)bh * W * C + c;
    float* q = out + (size_t)bh * W * C + c;
    float run = -FLT_MAX;
    for (int w = W - 1; w >= 0; --w) {
        run = fmaxf(run, p[w * C]);
        q[w * C] = run;
    }
}

__global__ __launch_bounds__(256) void k_hscan_add(const float* __restrict__ in,
                                                   float* __restrict__ out)
{
    int idx = blockIdx.x * 256 + threadIdx.x;   // b*(W*C) + w*C + c
    int wc = idx & (W * C - 1);
    int b  = idx >> 14;                          // W*C = 16384 = 2^14
    const float* p = in + (size_t)b * H * W * C + wc;
    float* q = out + (size_t)b * H * W * C + wc;
    float run = -FLT_MAX;
    for (int h = H - 1; h >= 0; --h) {
        run = fmaxf(run, p[(size_t)h * W * C]);
        q[(size_t)h * W * C] += run;
    }
}

extern "C" void kernel_launch(void* const* d_in, const int* in_sizes, int n_in,
                              void* d_out, int out_size, void* d_ws, size_t ws_size,
                              hipStream_t stream)
{
    const float* in = (const float*)d_in[0];
    float* out = (float*)d_out;

    const size_t tileElems = (size_t)B * NTH * W * C;     // 4,194,304 (= B*H*NTW*C too)
    const size_t need = 2 * tileElems * sizeof(float);    // 32 MiB

    if (ws_size >= need) {
        float* hTile = (float*)d_ws;
        float* wTile = hTile + tileElems;

        k_tilemax<<<B * NTH * (W / 64), 256, 0, stream>>>(in, hTile, wTile);
        // hTile: [B][16][W*C]  -> outer=B,    inner=W*C=2^14
        k_sufscan<<<(B * W * C + 255) / 256, 256, 0, stream>>>(hTile, B * W * C, 14);
        // wTile: [B*H][16][C]  -> outer=B*H,  inner=C=2^6
        k_sufscan<<<(B * H * C + 255) / 256, 256, 0, stream>>>(wTile, B * H * C, 6);
        k_final<<<B * NTH * (W / 64), 256, 0, stream>>>(in, hTile, wTile, out);
    } else {
        k_wscan<<<B * H * C / 256, 256, 0, stream>>>(in, out);
        k_hscan_add<<<B * W * C / 256, 256, 0, stream>>>(in, out);
    }
}

// Round 2
// 155.081 us; speedup vs baseline: 1.1162x; 1.1162x over previous
//
#include <hip/hip_runtime.h>
#include <float.h>

#define B 16
#define H 256
#define W 256
#define C 64
#define TH 16
#define TW 16
#define NTH (H / TH)   // 16 h-tiles
#define NTW (W / TW)   // 16 w-tiles

// ---------------------------------------------------------------------------
// k_tilemax: one pass over input.
//   hTile[b][t][w][c] = max over h in tile t of in[b,h,w,c]
//   wTile[b][h][s][c] = max over w in tile s of in[b,h,w,c]
// grid = B*NTH*(W/64) = 1024 blocks, 256 threads.
// thread: c = tid&63, wg = tid>>6; owns w = wq*64 + wg*16 + j, j in [0,16).
// All loads/stores: lane=c -> 256B coalesced per instruction.
// Input reads use NORMAL loads: we want the input resident in L3 for
// k_final's re-read.
// ---------------------------------------------------------------------------
__global__ __launch_bounds__(256) void k_tilemax(const float* __restrict__ in,
                                                 float* __restrict__ hTile,
                                                 float* __restrict__ wTile)
{
    int blk = blockIdx.x;
    int wq = blk & 3;                 // which 64-wide w chunk
    int t  = (blk >> 2) & (NTH - 1);  // h-tile
    int b  = blk >> 6;
    int tid = threadIdx.x;
    int c  = tid & 63;
    int wg = tid >> 6;                // 0..3
    int wbase = wq * 64 + wg * 16;
    int s = wbase / TW;               // w-tile index

    float hrun[16];
#pragma unroll
    for (int j = 0; j < 16; ++j) hrun[j] = -FLT_MAX;

    int h0 = t * TH;
    for (int hh = 0; hh < TH; ++hh) {
        int h = h0 + hh;
        const float* row = in + ((size_t)(b * H + h) * W + wbase) * C + c;
        float wmax = -FLT_MAX;
#pragma unroll
        for (int j = 0; j < 16; ++j) {
            float v = row[j * C];
            hrun[j] = fmaxf(hrun[j], v);
            wmax = fmaxf(wmax, v);
        }
        wTile[((size_t)(b * H + h) * NTW + s) * C + c] = wmax;
    }
    float* hout = hTile + ((size_t)(b * NTH + t) * W + wbase) * C + c;
#pragma unroll
    for (int j = 0; j < 16; ++j) hout[j * C] = hrun[j];
}

// ---------------------------------------------------------------------------
// k_sufscan2: both in-place EXCLUSIVE suffix-max scans in ONE dispatch.
//   hTile: [B][16][W*C]  inner = 2^14, total columns B*W*C = 262144
//   wTile: [B*H][16][C]  inner = 2^6,  total columns B*H*C = 262144
// grid = 2048 blocks * 256 threads; first 1024 blocks -> hTile, rest -> wTile.
// ---------------------------------------------------------------------------
__global__ __launch_bounds__(256) void k_sufscan2(float* __restrict__ hT,
                                                  float* __restrict__ wT)
{
    int idx = blockIdx.x * 256 + threadIdx.x;
    float* buf;
    int shift;
    if (idx < B * W * C) {            // block-uniform branch (1024*256 == B*W*C)
        buf = hT;  shift = 14;
    } else {
        buf = wT;  shift = 6;  idx -= B * W * C;
    }
    int inner = 1 << shift;
    int o = idx >> shift;
    int i = idx & (inner - 1);
    float* p = buf + ((size_t)o * 16) * inner + i;
    float v[16];
#pragma unroll
    for (int tt = 0; tt < 16; ++tt) v[tt] = p[tt * inner];
    float run = -FLT_MAX;
#pragma unroll
    for (int tt = 15; tt >= 0; --tt) {
        float nv = v[tt];
        v[tt] = run;              // exclusive: max over strictly-later tiles
        run = fmaxf(run, nv);
    }
#pragma unroll
    for (int tt = 0; tt < 16; ++tt) p[tt * inner] = v[tt];
}

// ---------------------------------------------------------------------------
// k_final: out = max(local h-suffix, hSuf) + max(local w-suffix, wSuf)
// Block index reversed so the input re-read starts at the L3-resident tail
// of k_tilemax's forward stream. Output stores are NON-TEMPORAL so the
// 256 MiB write stream does not evict the L3-resident input ahead of our
// own read pointer. Seed loads (read-once) are also non-temporal.
// ---------------------------------------------------------------------------
__global__ __launch_bounds__(256) void k_final(const float* __restrict__ in,
                                               const float* __restrict__ hSuf,
                                               const float* __restrict__ wSuf,
                                               float* __restrict__ out)
{
    int blk = (gridDim.x - 1) - blockIdx.x;   // reversed for L3 tail reuse
    int wq = blk & 3;
    int t  = (blk >> 2) & (NTH - 1);
    int b  = blk >> 6;
    int tid = threadIdx.x;
    int c  = tid & 63;
    int wg = tid >> 6;
    int wbase = wq * 64 + wg * 16;
    int s = wbase / TW;

    float hrun[16];
    const float* hs = hSuf + ((size_t)(b * NTH + t) * W + wbase) * C + c;
#pragma unroll
    for (int j = 0; j < 16; ++j) hrun[j] = __builtin_nontemporal_load(&hs[j * C]);

    int h0 = t * TH;
    for (int hh = TH - 1; hh >= 0; --hh) {
        int h = h0 + hh;
        const float* row = in + ((size_t)(b * H + h) * W + wbase) * C + c;
        float v[16];
#pragma unroll
        for (int j = 0; j < 16; ++j) {
            v[j] = row[j * C];                 // NORMAL load: want L3 hits
            hrun[j] = fmaxf(hrun[j], v[j]);
        }
        float ws = __builtin_nontemporal_load(
            &wSuf[((size_t)(b * H + h) * NTW + s) * C + c]);
        float* orow = out + ((size_t)(b * H + h) * W + wbase) * C + c;
#pragma unroll
        for (int j = 15; j >= 0; --j) {
            ws = fmaxf(ws, v[j]);
            __builtin_nontemporal_store(hrun[j] + ws, &orow[j * C]);
        }
    }
}

// ---------------------------------------------------------------------------
// Fallback (no workspace): two serial-scan kernels, fully coalesced.
// ---------------------------------------------------------------------------
__global__ __launch_bounds__(256) void k_wscan(const float* __restrict__ in,
                                               float* __restrict__ out)
{
    int idx = blockIdx.x * 256 + threadIdx.x;   // (b*H + h)*C + c
    int c  = idx & 63;
    int bh = idx >> 6;
    const float* p = in + (size_t)bh * W * C + c;
    float* q = out + (size_t)bh * W * C + c;
    float run = -FLT_MAX;
    for (int w = W - 1; w >= 0; --w) {
        run = fmaxf(run, p[w * C]);
        q[w * C] = run;
    }
}

__global__ __launch_bounds__(256) void k_hscan_add(const float* __restrict__ in,
                                                   float* __restrict__ out)
{
    int idx = blockIdx.x * 256 + threadIdx.x;   // b*(W*C) + w*C + c
    int wc = idx & (W * C - 1);
    int b  = idx >> 14;                          // W*C = 16384 = 2^14
    const float* p = in + (size_t)b * H * W * C + wc;
    float* q = out + (size_t)b * H * W * C + wc;
    float run = -FLT_MAX;
    for (int h = H - 1; h >= 0; --h) {
        run = fmaxf(run, p[(size_t)h * W * C]);
        q[(size_t)h * W * C] += run;
    }
}

extern "C" void kernel_launch(void* const* d_in, const int* in_sizes, int n_in,
                              void* d_out, int out_size, void* d_ws, size_t ws_size,
                              hipStream_t stream)
{
    const float* in = (const float*)d_in[0];
    float* out = (float*)d_out;

    const size_t tileElems = (size_t)B * NTH * W * C;     // 4,194,304 (= B*H*NTW*C too)
    const size_t need = 2 * tileElems * sizeof(float);    // 32 MiB

    if (ws_size >= need) {
        float* hTile = (float*)d_ws;
        float* wTile = hTile + tileElems;

        k_tilemax<<<B * NTH * (W / 64), 256, 0, stream>>>(in, hTile, wTile);
        k_sufscan2<<<2 * B * W * C / 256, 256, 0, stream>>>(hTile, wTile);
        k_final<<<B * NTH * (W / 64), 256, 0, stream>>>(in, hTile, wTile, out);
    } else {
        k_wscan<<<B * H * C / 256, 256, 0, stream>>>(in, out);
        k_hscan_add<<<B * W * C / 256, 256, 0, stream>>>(in, out);
    }
}